// Round 2
// baseline (353.444 us; speedup 1.0000x reference)
//
#include <hip/hip_runtime.h>
#include <math.h>

#define BN_EPS 1e-5f

// ws layout (floats):
//   [0, N)        S      - scatter sum of raw edge_attr per dst node
//   [N, 2N)       cnt    - in-degree per node (as float)
//   [2N, 2N+16)   stats  - 0..4 xsum, 5..9 xsumsq, 10 esum, 11 esumsq
//   [2N+16, +48)  params - 0..24 A (folded 5x5), 25..29 c, 30..34 we1, 35 se, 36 te

__global__ void stats_x_kernel(const float* __restrict__ x, int N,
                               float* __restrict__ stats) {
    float s[5] = {0, 0, 0, 0, 0};
    float q[5] = {0, 0, 0, 0, 0};
    int stride = gridDim.x * blockDim.x;
    for (int n = blockIdx.x * blockDim.x + threadIdx.x; n < N; n += stride) {
#pragma unroll
        for (int j = 0; j < 5; ++j) {
            float v = x[n * 5 + j];
            s[j] += v;
            q[j] += v * v;
        }
    }
    // wave64 reduce
#pragma unroll
    for (int j = 0; j < 5; ++j) {
        for (int d = 32; d >= 1; d >>= 1) {
            s[j] += __shfl_down(s[j], d);
            q[j] += __shfl_down(q[j], d);
        }
    }
    __shared__ float bs[4][10];
    int lane = threadIdx.x & 63;
    int wid = threadIdx.x >> 6;
    if (lane == 0) {
#pragma unroll
        for (int j = 0; j < 5; ++j) {
            bs[wid][j] = s[j];
            bs[wid][5 + j] = q[j];
        }
    }
    __syncthreads();
    if (threadIdx.x < 10) {
        float t = 0;
#pragma unroll
        for (int w = 0; w < 4; ++w) t += bs[w][threadIdx.x];
        atomicAdd(&stats[threadIdx.x], t);
    }
}

__global__ void edge_kernel(const float* __restrict__ ea,
                            const int* __restrict__ dst, int E,
                            float* __restrict__ S, float* __restrict__ cnt,
                            float* __restrict__ stats) {
    float s = 0, q = 0;
    int stride = gridDim.x * blockDim.x;
    for (int e = blockIdx.x * blockDim.x + threadIdx.x; e < E; e += stride) {
        float v = ea[e];
        int d = dst[e];
        s += v;
        q += v * v;
        atomicAdd(&S[d], v);
        atomicAdd(&cnt[d], 1.0f);
    }
    for (int d = 32; d >= 1; d >>= 1) {
        s += __shfl_down(s, d);
        q += __shfl_down(q, d);
    }
    __shared__ float bs[4][2];
    int lane = threadIdx.x & 63;
    int wid = threadIdx.x >> 6;
    if (lane == 0) {
        bs[wid][0] = s;
        bs[wid][1] = q;
    }
    __syncthreads();
    if (threadIdx.x == 0) {
        float ts = 0, tq = 0;
#pragma unroll
        for (int w = 0; w < 4; ++w) {
            ts += bs[w][0];
            tq += bs[w][1];
        }
        atomicAdd(&stats[10], ts);
        atomicAdd(&stats[11], tq);
    }
}

__global__ void finalize_kernel(const float* __restrict__ gx, const float* __restrict__ bx,
                                const float* __restrict__ ge, const float* __restrict__ be,
                                const float* __restrict__ Wg, const float* __restrict__ bg,
                                const float* __restrict__ We, const float* __restrict__ W1,
                                const float* __restrict__ b1,
                                const float* __restrict__ stats,
                                float* __restrict__ params, int N, int E) {
    __shared__ float Ms[25], sc[5], sh[5], bg1s[5], we1s[5];
    int t = threadIdx.x;
    if (t < 5) {
        float mu = stats[t] / (float)N;
        float var = stats[5 + t] / (float)N - mu * mu;
        float s = gx[t] * rsqrtf(var + BN_EPS);
        sc[t] = s;
        sh[t] = bx[t] - mu * s;
    }
    if (t < 25) {
        int j = t / 5, i = t % 5;
        float acc = 0;
        for (int k = 0; k < 110; ++k) acc += Wg[j * 110 + k] * W1[k * 5 + i];
        Ms[t] = acc;
    }
    if (t >= 25 && t < 30) {
        int i = t - 25;
        float acc = 0;
        for (int k = 0; k < 110; ++k) acc += We[k] * W1[k * 5 + i];
        we1s[i] = acc;
    }
    if (t >= 30 && t < 35) {
        int i = t - 30;
        float acc = 0;
        for (int k = 0; k < 110; ++k) acc += bg[k] * W1[k * 5 + i];
        bg1s[i] = acc;
    }
    __syncthreads();
    if (t < 25) params[t] = sc[t / 5] * Ms[t];
    if (t < 5) {
        float acc = bg1s[t] + b1[t];
#pragma unroll
        for (int j = 0; j < 5; ++j) acc += sh[j] * Ms[j * 5 + t];
        params[25 + t] = acc;
        params[30 + t] = we1s[t];
    }
    if (t == 35) {
        float mu = stats[10] / (float)E;
        float var = stats[11] / (float)E - mu * mu;
        float s = ge[0] * rsqrtf(var + BN_EPS);
        params[35] = s;
        params[36] = be[0] - mu * s;
    }
}

__global__ void node_kernel(const float* __restrict__ x, const int* __restrict__ batch,
                            const float* __restrict__ S, const float* __restrict__ cnt,
                            const float* __restrict__ params,
                            const float* __restrict__ W2, const float* __restrict__ b2,
                            float* __restrict__ out, int N) {
    __shared__ float P[37], W2s[25], b2s[5];
    int tid = threadIdx.x;
    if (tid < 37) P[tid] = params[tid];
    if (tid < 25) W2s[tid] = W2[tid];
    if (tid < 5) b2s[tid] = b2[tid];
    __syncthreads();

    int n = blockIdx.x * blockDim.x + tid;
    int lane = tid & 63;
    int b = -1;
    float o[5] = {0, 0, 0, 0, 0};
    if (n < N) {
        b = batch[n];
        float msg = P[35] * S[n] + P[36] * cnt[n];
        float r[5];
#pragma unroll
        for (int i = 0; i < 5; ++i) r[i] = P[25 + i] + msg * P[30 + i];
#pragma unroll
        for (int j = 0; j < 5; ++j) {
            float xv = x[n * 5 + j];
#pragma unroll
            for (int i = 0; i < 5; ++i) r[i] += xv * P[j * 5 + i];
        }
#pragma unroll
        for (int i = 0; i < 5; ++i) {
            float v = r[i];
            r[i] = v / (1.0f + __expf(-v));  // swish
        }
#pragma unroll
        for (int i = 0; i < 5; ++i) {
            float acc = b2s[i];
#pragma unroll
            for (int k = 0; k < 5; ++k) acc += r[k] * W2s[k * 5 + i];
            o[i] = acc;
        }
    }

    // wave-level segmented reduction (batch is sorted -> segments contiguous)
#pragma unroll
    for (int d = 1; d < 64; d <<= 1) {
        int nb = __shfl_down(b, d);
        float t0 = __shfl_down(o[0], d);
        float t1 = __shfl_down(o[1], d);
        float t2 = __shfl_down(o[2], d);
        float t3 = __shfl_down(o[3], d);
        float t4 = __shfl_down(o[4], d);
        if (lane + d < 64 && nb == b) {
            o[0] += t0; o[1] += t1; o[2] += t2; o[3] += t3; o[4] += t4;
        }
    }
    int pb = __shfl_up(b, 1);
    bool head = (lane == 0) || (pb != b);
    if (head && b >= 0) {
#pragma unroll
        for (int i = 0; i < 5; ++i) atomicAdd(&out[b * 5 + i], o[i]);
    }
}

extern "C" void kernel_launch(void* const* d_in, const int* in_sizes, int n_in,
                              void* d_out, int out_size, void* d_ws, size_t ws_size,
                              hipStream_t stream) {
    const float* x = (const float*)d_in[0];
    const float* ea = (const float*)d_in[1];
    const int* batch = (const int*)d_in[2];
    const int* ei = (const int*)d_in[3];
    const float* gx = (const float*)d_in[4];
    const float* bx = (const float*)d_in[5];
    const float* ge = (const float*)d_in[6];
    const float* be = (const float*)d_in[7];
    const float* Wg = (const float*)d_in[8];
    const float* bg = (const float*)d_in[9];
    const float* We = (const float*)d_in[10];
    const float* W1 = (const float*)d_in[11];
    const float* b1 = (const float*)d_in[12];
    const float* W2 = (const float*)d_in[13];
    const float* b2 = (const float*)d_in[14];

    int N = in_sizes[2];   // n_nodes
    int E = in_sizes[1];   // n_edges

    float* ws = (float*)d_ws;
    float* Sbuf = ws;
    float* cntbuf = ws + N;
    float* stats = ws + 2LL * N;
    float* params = stats + 16;
    float* out = (float*)d_out;

    hipMemsetAsync(d_ws, 0, (2LL * N + 64) * sizeof(float), stream);
    hipMemsetAsync(d_out, 0, (size_t)out_size * sizeof(float), stream);

    stats_x_kernel<<<1024, 256, 0, stream>>>(x, N, stats);
    edge_kernel<<<1024, 256, 0, stream>>>(ea, ei + E, E, Sbuf, cntbuf, stats);
    finalize_kernel<<<1, 64, 0, stream>>>(gx, bx, ge, be, Wg, bg, We, W1, b1,
                                          stats, params, N, E);
    node_kernel<<<(N + 255) / 256, 256, 0, stream>>>(x, batch, Sbuf, cntbuf,
                                                     params, W2, b2, out, N);
}

// Round 3
// 247.818 us; speedup vs baseline: 1.4262x; 1.4262x over previous
//
#include <hip/hip_runtime.h>
#include <math.h>

#define BN_EPS 1e-5f

// ws layout (floats):
//   [0, N)        M      - folded message per node: sum over in-edges of (se*ea+te)
//   [N, N+16)     stats  - 0..4 xsum, 5..9 xsumsq, 10 esum, 11 esumsq
//   [N+16, N+64)  params - 0..24 A (folded 5x5), 25..29 c, 30..34 we1, 35 se, 36 te

__global__ void stats_kernel(const float* __restrict__ x, int N,
                             const float* __restrict__ ea, int E,
                             float* __restrict__ stats) {
    float s[5] = {0, 0, 0, 0, 0};
    float q[5] = {0, 0, 0, 0, 0};
    float es = 0, eq = 0;
    int tid = blockIdx.x * blockDim.x + threadIdx.x;
    int stride = gridDim.x * blockDim.x;

    // x: 5N floats, process 20-float chunks (4 nodes) with float4 loads.
    int nchunks = (int)((5LL * N) / 20);
    for (int c = tid; c < nchunks; c += stride) {
        const float4* p = (const float4*)(x + 20LL * c);
        float4 a0 = p[0], a1 = p[1], a2 = p[2], a3 = p[3], a4 = p[4];
        // feature = offset mod 5 (static mapping)
        s[0] += a0.x + a1.y + a2.z + a3.w;
        q[0] += a0.x * a0.x + a1.y * a1.y + a2.z * a2.z + a3.w * a3.w;
        s[1] += a0.y + a1.z + a2.w + a4.x;
        q[1] += a0.y * a0.y + a1.z * a1.z + a2.w * a2.w + a4.x * a4.x;
        s[2] += a0.z + a1.w + a3.x + a4.y;
        q[2] += a0.z * a0.z + a1.w * a1.w + a3.x * a3.x + a4.y * a4.y;
        s[3] += a0.w + a2.x + a3.y + a4.z;
        q[3] += a0.w * a0.w + a2.x * a2.x + a3.y * a3.y + a4.z * a4.z;
        s[4] += a1.x + a2.y + a3.z + a4.w;
        q[4] += a1.x * a1.x + a2.y * a2.y + a3.z * a3.z + a4.w * a4.w;
    }
    // tail nodes (if N % 4 != 0)
    for (int n = nchunks * 4 + tid; n < N; n += stride) {
#pragma unroll
        for (int j = 0; j < 5; ++j) {
            float v = x[n * 5 + j];
            s[j] += v;
            q[j] += v * v;
        }
    }
    // edge_attr stats, float4
    int evec = E >> 2;
    for (int c = tid; c < evec; c += stride) {
        float4 v = ((const float4*)ea)[c];
        es += v.x + v.y + v.z + v.w;
        eq += v.x * v.x + v.y * v.y + v.z * v.z + v.w * v.w;
    }
    for (int e = (evec << 2) + tid; e < E; e += stride) {
        float v = ea[e];
        es += v;
        eq += v * v;
    }

    // wave64 reduce 12 values
    float vals[12] = {s[0], s[1], s[2], s[3], s[4], q[0], q[1], q[2], q[3], q[4], es, eq};
#pragma unroll
    for (int j = 0; j < 12; ++j) {
        for (int d = 32; d >= 1; d >>= 1) vals[j] += __shfl_down(vals[j], d);
    }
    __shared__ float bs[4][12];
    int lane = threadIdx.x & 63;
    int wid = threadIdx.x >> 6;
    if (lane == 0) {
#pragma unroll
        for (int j = 0; j < 12; ++j) bs[wid][j] = vals[j];
    }
    __syncthreads();
    if (threadIdx.x < 12) {
        float t = 0;
#pragma unroll
        for (int w = 0; w < 4; ++w) t += bs[w][threadIdx.x];
        atomicAdd(&stats[threadIdx.x], t);
    }
}

__global__ void finalize_kernel(const float* __restrict__ gx, const float* __restrict__ bx,
                                const float* __restrict__ ge, const float* __restrict__ be,
                                const float* __restrict__ Wg, const float* __restrict__ bg,
                                const float* __restrict__ We, const float* __restrict__ W1,
                                const float* __restrict__ b1,
                                const float* __restrict__ stats,
                                float* __restrict__ params, int N, int E) {
    __shared__ float Ms[25], sc[5], sh[5], bg1s[5], we1s[5];
    int t = threadIdx.x;
    if (t < 5) {
        float mu = stats[t] / (float)N;
        float var = stats[5 + t] / (float)N - mu * mu;
        float s = gx[t] * rsqrtf(var + BN_EPS);
        sc[t] = s;
        sh[t] = bx[t] - mu * s;
    }
    if (t < 25) {
        int j = t / 5, i = t % 5;
        float acc = 0;
        for (int k = 0; k < 110; ++k) acc += Wg[j * 110 + k] * W1[k * 5 + i];
        Ms[t] = acc;
    }
    if (t >= 25 && t < 30) {
        int i = t - 25;
        float acc = 0;
        for (int k = 0; k < 110; ++k) acc += We[k] * W1[k * 5 + i];
        we1s[i] = acc;
    }
    if (t >= 30 && t < 35) {
        int i = t - 30;
        float acc = 0;
        for (int k = 0; k < 110; ++k) acc += bg[k] * W1[k * 5 + i];
        bg1s[i] = acc;
    }
    __syncthreads();
    if (t < 25) params[t] = sc[t / 5] * Ms[t];
    if (t < 5) {
        float acc = bg1s[t] + b1[t];
#pragma unroll
        for (int j = 0; j < 5; ++j) acc += sh[j] * Ms[j * 5 + t];
        params[25 + t] = acc;
        params[30 + t] = we1s[t];
    }
    if (t == 35) {
        float mu = stats[10] / (float)E;
        float var = stats[11] / (float)E - mu * mu;
        float s = ge[0] * rsqrtf(var + BN_EPS);
        params[35] = s;               // se
        params[36] = be[0] - mu * s;  // te
    }
}

__global__ void scatter_kernel(const float* __restrict__ ea, const int* __restrict__ dst,
                               int E, const float* __restrict__ params,
                               float* __restrict__ M) {
    float se = params[35];
    float te = params[36];
    int tid = blockIdx.x * blockDim.x + threadIdx.x;
    int stride = gridDim.x * blockDim.x;
    int evec = E >> 2;
    for (int c = tid; c < evec; c += stride) {
        float4 v = ((const float4*)ea)[c];
        int4 d = ((const int4*)dst)[c];
        atomicAdd(&M[d.x], se * v.x + te);
        atomicAdd(&M[d.y], se * v.y + te);
        atomicAdd(&M[d.z], se * v.z + te);
        atomicAdd(&M[d.w], se * v.w + te);
    }
    for (int e = (evec << 2) + tid; e < E; e += stride) {
        atomicAdd(&M[dst[e]], se * ea[e] + te);
    }
}

__global__ void node_kernel(const float* __restrict__ x, const int* __restrict__ batch,
                            const float* __restrict__ M,
                            const float* __restrict__ params,
                            const float* __restrict__ W2, const float* __restrict__ b2,
                            float* __restrict__ out, int N) {
    __shared__ float P[37], W2s[25], b2s[5];
    int tid = threadIdx.x;
    if (tid < 37) P[tid] = params[tid];
    if (tid < 25) W2s[tid] = W2[tid];
    if (tid < 5) b2s[tid] = b2[tid];
    __syncthreads();

    int n = blockIdx.x * blockDim.x + tid;
    int lane = tid & 63;
    int b = -1;
    float o[5] = {0, 0, 0, 0, 0};
    if (n < N) {
        b = batch[n];
        float msg = M[n];
        float r[5];
#pragma unroll
        for (int i = 0; i < 5; ++i) r[i] = P[25 + i] + msg * P[30 + i];
#pragma unroll
        for (int j = 0; j < 5; ++j) {
            float xv = x[n * 5 + j];
#pragma unroll
            for (int i = 0; i < 5; ++i) r[i] += xv * P[j * 5 + i];
        }
#pragma unroll
        for (int i = 0; i < 5; ++i) {
            float v = r[i];
            r[i] = v / (1.0f + __expf(-v));  // swish
        }
#pragma unroll
        for (int i = 0; i < 5; ++i) {
            float acc = b2s[i];
#pragma unroll
            for (int k = 0; k < 5; ++k) acc += r[k] * W2s[k * 5 + i];
            o[i] = acc;
        }
    }

    // wave-level segmented reduction (batch sorted -> contiguous segments)
#pragma unroll
    for (int d = 1; d < 64; d <<= 1) {
        int nb = __shfl_down(b, d);
        float t0 = __shfl_down(o[0], d);
        float t1 = __shfl_down(o[1], d);
        float t2 = __shfl_down(o[2], d);
        float t3 = __shfl_down(o[3], d);
        float t4 = __shfl_down(o[4], d);
        if (lane + d < 64 && nb == b) {
            o[0] += t0; o[1] += t1; o[2] += t2; o[3] += t3; o[4] += t4;
        }
    }
    int pb = __shfl_up(b, 1);
    bool head = (lane == 0) || (pb != b);
    if (head && b >= 0) {
#pragma unroll
        for (int i = 0; i < 5; ++i) atomicAdd(&out[b * 5 + i], o[i]);
    }
}

extern "C" void kernel_launch(void* const* d_in, const int* in_sizes, int n_in,
                              void* d_out, int out_size, void* d_ws, size_t ws_size,
                              hipStream_t stream) {
    const float* x = (const float*)d_in[0];
    const float* ea = (const float*)d_in[1];
    const int* batch = (const int*)d_in[2];
    const int* ei = (const int*)d_in[3];
    const float* gx = (const float*)d_in[4];
    const float* bx = (const float*)d_in[5];
    const float* ge = (const float*)d_in[6];
    const float* be = (const float*)d_in[7];
    const float* Wg = (const float*)d_in[8];
    const float* bg = (const float*)d_in[9];
    const float* We = (const float*)d_in[10];
    const float* W1 = (const float*)d_in[11];
    const float* b1 = (const float*)d_in[12];
    const float* W2 = (const float*)d_in[13];
    const float* b2 = (const float*)d_in[14];

    int N = in_sizes[2];  // n_nodes
    int E = in_sizes[1];  // n_edges

    float* ws = (float*)d_ws;
    float* M = ws;
    float* stats = ws + N;
    float* params = stats + 16;
    float* out = (float*)d_out;

    hipMemsetAsync(d_ws, 0, ((size_t)N + 64) * sizeof(float), stream);
    hipMemsetAsync(d_out, 0, (size_t)out_size * sizeof(float), stream);

    stats_kernel<<<1024, 256, 0, stream>>>(x, N, ea, E, stats);
    finalize_kernel<<<1, 64, 0, stream>>>(gx, bx, ge, be, Wg, bg, We, W1, b1,
                                          stats, params, N, E);
    scatter_kernel<<<2048, 256, 0, stream>>>(ea, ei + E, E, params, M);
    node_kernel<<<(N + 255) / 256, 256, 0, stream>>>(x, batch, M, params, W2, b2, out, N);
}